// Round 3
// baseline (23.008 us; speedup 1.0000x reference)
//
#include <hip/hip_runtime.h>
#include <math.h>

// HybridSymmetricLoss: B=8192, P=4, M=12, 24 perms.
// pairS[p][q] = sum_{i,j} (y[p] ? log a[q] : log1p(-a[q]))  (negated BCE)
// best perm = argmax_sigma sum_p pairS[p][sigma(p)]; category BCE via sigma.
// Single kernel: per-batch value -> fixed-point (2^-42) ull atomics ->
// last block writes scalar. Deterministic (integer adds commute).

#define LOG2_CLIP (-144.26950408889634f)   // -100 / ln(2)
#define LN2F      (0.6931471805599453f)
#define FIXSCALE  (4398046511104.0)        // 2^42

// perm table, lexicographic. byte p = 8*p + 2*sigma(p) = gather lane (lo 5 bits);
// sigma(p) = (byte_p >> 1) & 3.
#define PK(a,b,c,d) ((unsigned)((2u*(a)) | ((8u+2u*(b))<<8) | \
                                ((16u+2u*(c))<<16) | ((24u+2u*(d))<<24)))
__device__ const unsigned PERM_PK[32] = {
    PK(0,1,2,3), PK(0,1,3,2), PK(0,2,1,3), PK(0,2,3,1), PK(0,3,1,2), PK(0,3,2,1),
    PK(1,0,2,3), PK(1,0,3,2), PK(1,2,0,3), PK(1,2,3,0), PK(1,3,0,2), PK(1,3,2,0),
    PK(2,0,1,3), PK(2,0,3,1), PK(2,1,0,3), PK(2,1,3,0), PK(2,3,0,1), PK(2,3,1,0),
    PK(3,0,1,2), PK(3,0,2,1), PK(3,1,0,2), PK(3,1,2,0), PK(3,2,0,1), PK(3,2,1,0),
    PK(0,1,2,3), PK(0,1,2,3), PK(0,1,2,3), PK(0,1,2,3),
    PK(0,1,2,3), PK(0,1,2,3), PK(0,1,2,3), PK(0,1,2,3)
};

__global__ __launch_bounds__(1024, 4) void hsl_fused(
    const float* __restrict__ assign,    // [B,4,12,12]
    const float* __restrict__ cat,       // [B,4]
    const float* __restrict__ alabels,   // [B,4,12,12]
    const float* __restrict__ clabels,   // [B,4]
    unsigned long long* __restrict__ acc,     // [0]=sum fixp, [1]=ticket
    float* __restrict__ out,
    int B, int nblocks)
{
    __shared__ unsigned long long lred[32];

    const int tid   = (int)threadIdx.x;
    const int wave  = tid >> 6;                 // 0..15
    const int lane  = tid & 63;
    const int half  = lane >> 5;                // 0/1: which batch in wave
    const int l32   = lane & 31;
    // 32 batches per block: 2 per wave
    const int b = (int)blockIdx.x * 32 + wave * 2 + half;

    const float* __restrict__ A = assign  + (size_t)b * 576;
    const float* __restrict__ Y = alabels + (size_t)b * 576;

    // s[4p+q] += y[p]*(la[q]-lb[q]);  T[q] += lb[q]   (log2 domain)
    float s[16], T[4];
#pragma unroll
    for (int i = 0; i < 16; ++i) s[i] = 0.0f;
#pragma unroll
    for (int i = 0; i < 4; ++i) T[i] = 0.0f;

#pragma unroll
    for (int it = 0; it < 5; ++it) {
        if (it < 4 || l32 < 16) {               // e = l32 + 32*it < 144
            const int e = l32 + it * 32;
            float d[4], y[4];
#pragma unroll
            for (int q = 0; q < 4; ++q) {
                const float a  = A[q * 144 + e];
                const float la = fmaxf(__log2f(a),        LOG2_CLIP);
                const float lb = fmaxf(__log2f(1.0f - a), LOG2_CLIP);
                d[q] = la - lb;
                T[q] += lb;
            }
#pragma unroll
            for (int p = 0; p < 4; ++p) y[p] = Y[p * 144 + e];
#pragma unroll
            for (int p = 0; p < 4; ++p)
#pragma unroll
                for (int q = 0; q < 4; ++q)
                    s[p * 4 + q] = fmaf(y[p], d[q], s[p * 4 + q]);
        }
    }
#pragma unroll
    for (int i = 0; i < 16; ++i) s[i] += T[i & 3];

    // reduce-scatter within each 32-lane half (masks 16,8,4,2), then mask 1.
    // result: lane l holds total S[l32 >> 1].
    const bool h16 = (lane & 16) != 0;
    const bool h8  = (lane & 8)  != 0;
    const bool h4  = (lane & 4)  != 0;
    const bool h2  = (lane & 2)  != 0;

    float t[8];
#pragma unroll
    for (int i = 0; i < 8; ++i) {
        const float keep = h16 ? s[i + 8] : s[i];
        const float send = h16 ? s[i]     : s[i + 8];
        t[i] = keep + __shfl_xor(send, 16, 64);
    }
    float u[4];
#pragma unroll
    for (int i = 0; i < 4; ++i) {
        const float keep = h8 ? t[i + 4] : t[i];
        const float send = h8 ? t[i]     : t[i + 4];
        u[i] = keep + __shfl_xor(send, 8, 64);
    }
    float w[2];
#pragma unroll
    for (int i = 0; i < 2; ++i) {
        const float keep = h4 ? u[i + 2] : u[i];
        const float send = h4 ? u[i]     : u[i + 2];
        w[i] = keep + __shfl_xor(send, 4, 64);
    }
    float x;
    {
        const float keep = h2 ? w[1] : w[0];
        const float send = h2 ? w[0] : w[1];
        x = keep + __shfl_xor(send, 2, 64);
    }
    x += __shfl_xor(x, 1, 64);
    // lane l: x == total S[l32>>1]

    // perm-parallel scoring: lane j<24 of each half evaluates perm j
    unsigned pk = PERM_PK[l32];
    const int hb = (int)(lane & 32);
    const float v0 = __shfl(x, hb + (int)( pk        & 0xFFu), 64);
    const float v1 = __shfl(x, hb + (int)((pk >> 8)  & 0xFFu), 64);
    const float v2 = __shfl(x, hb + (int)((pk >> 16) & 0xFFu), 64);
    const float v3 = __shfl(x, hb + (int)( pk >> 24        ), 64);
    float score = (v0 + v1) + (v2 + v3);
    if (l32 >= 24) score = -__builtin_huge_valf();

    // max-butterfly within each 32-half, carry pk
#pragma unroll
    for (int m = 16; m >= 1; m >>= 1) {
        const float    os  = __shfl_xor(score, m, 64);
        const unsigned opk = __shfl_xor(pk,    m, 64);
        const bool take = os > score;
        score = take ? os  : score;
        pk    = take ? opk : pk;
    }

    if (l32 == 0) {
        const float* __restrict__ C  = cat     + (size_t)b * 4;
        const float* __restrict__ CY = clabels + (size_t)b * 4;
        float cs2 = 0.0f;
#pragma unroll
        for (int p = 0; p < 4; ++p) {
            const int q  = (int)((pk >> (8 * p + 1)) & 3u);
            const float c  = C[q];
            const float yv = CY[p];
            const float l2 = (yv != 0.0f) ? fmaxf(__log2f(c), LOG2_CLIP)
                                          : fmaxf(__log2f(1.0f - c), LOG2_CLIP);
            cs2 += l2;
        }
        // per-batch contribution: -ln2 * (score/576 + cs2/8)   (>= 0)
        const float val = -LN2F * (score * (1.0f / 576.0f) + 0.125f * cs2);
        lred[tid >> 5] = (unsigned long long)((double)val * FIXSCALE + 0.5);
    }
    __syncthreads();

    // block reduce 32 fixed-point values -> one atomic
    if (tid < 32) {
        unsigned long long v = lred[tid];
#pragma unroll
        for (int m = 16; m >= 1; m >>= 1)
            v += __shfl_xor(v, m, 64);
        if (tid == 0) {
            atomicAdd(&acc[0], v);
            __threadfence();
            const unsigned long long ticket = atomicAdd(&acc[1], 1ULL);
            if (ticket == (unsigned long long)(nblocks - 1)) {
                const unsigned long long total = atomicAdd(&acc[0], 0ULL);
                out[0] = (float)((double)total / FIXSCALE / (double)B);
            }
        }
    }
}

extern "C" void kernel_launch(void* const* d_in, const int* in_sizes, int n_in,
                              void* d_out, int out_size, void* d_ws, size_t ws_size,
                              hipStream_t stream) {
    const float* assign  = (const float*)d_in[0];
    const float* cat     = (const float*)d_in[1];
    const float* alabels = (const float*)d_in[2];
    const float* clabels = (const float*)d_in[3];
    float* out = (float*)d_out;

    const int B = in_sizes[0] / 576;  // 8192
    unsigned long long* acc = (unsigned long long*)d_ws;

    hipMemsetAsync(acc, 0, 16, stream);

    const int nblocks = B / 32;       // 32 batches per 1024-thread block
    hipLaunchKernelGGL(hsl_fused, dim3(nblocks), dim3(1024), 0, stream,
                       assign, cat, alabels, clabels, acc, out, B, nblocks);
}